// Round 2
// baseline (287.414 us; speedup 1.0000x reference)
//
#include <hip/hip_runtime.h>
#include <hip/hip_bf16.h>

// Problem constants
#define B 32
#define T 4096
#define E 1024
#define H 1024

// ws layout (in floats). qkv: p=0 -> v, p=1 -> k, p=2 -> q
#define OFF_QKV    0                               // 3*32*1024   =  98304
#define OFF_SCORES (3 * B * H)                     // 32*4096     = 131072
#define ATTN_STRIDE 4104
#define OFF_ATTN   (OFF_SCORES + B * T)            // 32*4104     = 131328
#define NTC        64                              // t-chunks for PV
#define OFF_PART2  (OFF_ATTN + B * ATTN_STRIDE)    // 32*64*1024  = 2097152

__device__ __forceinline__ float wred(float v) {
#pragma unroll
    for (int m = 32; m; m >>= 1) v += __shfl_xor(v, m, 64);
    return v;
}

// ---------------------------------------------------------------------------
// Kernel 1: fused projection. grid (16 hc, 3 p, 2 bg), block 256.
// wave handles 4 batches x 64 h-columns over full K=1024.
__global__ __launch_bounds__(256) void proj_fused(const float* __restrict__ x,
                                                  const float* __restrict__ Wv,
                                                  const float* __restrict__ Wk,
                                                  const float* __restrict__ Wq,
                                                  float* __restrict__ qkv) {
    const int hc = blockIdx.x;
    const int p  = blockIdx.y;
    const int bg = blockIdx.z;
    const float* __restrict__ W = (p == 0) ? Wv : ((p == 1) ? Wk : Wq);

    const int wave = threadIdx.x >> 6;
    const int lane = threadIdx.x & 63;
    const int h  = hc * 64 + lane;
    const int b0 = bg * 16 + wave * 4;

    float acc0 = 0.f, acc1 = 0.f, acc2 = 0.f, acc3 = 0.f;

    for (int e = 0; e < E; e += 4) {
        const float w0 = W[(size_t)(e + 0) * H + h];
        const float w1 = W[(size_t)(e + 1) * H + h];
        const float w2 = W[(size_t)(e + 2) * H + h];
        const float w3 = W[(size_t)(e + 3) * H + h];
        const float4 x0 = *reinterpret_cast<const float4*>(&x[(b0 + 0) * E + e]);
        const float4 x1 = *reinterpret_cast<const float4*>(&x[(b0 + 1) * E + e]);
        const float4 x2 = *reinterpret_cast<const float4*>(&x[(b0 + 2) * E + e]);
        const float4 x3 = *reinterpret_cast<const float4*>(&x[(b0 + 3) * E + e]);
        acc0 += x0.x * w0 + x0.y * w1 + x0.z * w2 + x0.w * w3;
        acc1 += x1.x * w0 + x1.y * w1 + x1.z * w2 + x1.w * w3;
        acc2 += x2.x * w0 + x2.y * w1 + x2.z * w2 + x2.w * w3;
        acc3 += x3.x * w0 + x3.y * w1 + x3.z * w2 + x3.w * w3;
    }
    qkv[(size_t)p * (B * H) + (b0 + 0) * H + h] = acc0;
    qkv[(size_t)p * (B * H) + (b0 + 1) * H + h] = acc1;
    qkv[(size_t)p * (B * H) + (b0 + 2) * H + h] = acc2;
    qkv[(size_t)p * (B * H) + (b0 + 3) * H + h] = acc3;
}

// ---------------------------------------------------------------------------
// Kernel 2: scores[b][t] = dot(key_cache[b][t][:], q[b][:]).
// grid (T/64, B), block 256 (4 waves); wave = 16 rows in 4 groups of 4.
__global__ __launch_bounds__(256) void scores_kernel(const float* __restrict__ kc,
                                                     const float* __restrict__ q,
                                                     float* __restrict__ scores) {
    __shared__ float4 qs4[256];
    const int b = blockIdx.y;
    qs4[threadIdx.x] = reinterpret_cast<const float4*>(q + (size_t)b * H)[threadIdx.x];
    __syncthreads();

    const int wave = threadIdx.x >> 6;
    const int lane = threadIdx.x & 63;
    const int t0   = blockIdx.x * 64 + wave * 16;

#pragma unroll
    for (int rg = 0; rg < 4; ++rg) {
        const int tb = t0 + rg * 4;
        const float4* __restrict__ r0 = reinterpret_cast<const float4*>(kc + ((size_t)b * T + tb + 0) * H);
        const float4* __restrict__ r1 = reinterpret_cast<const float4*>(kc + ((size_t)b * T + tb + 1) * H);
        const float4* __restrict__ r2 = reinterpret_cast<const float4*>(kc + ((size_t)b * T + tb + 2) * H);
        const float4* __restrict__ r3 = reinterpret_cast<const float4*>(kc + ((size_t)b * T + tb + 3) * H);
        float a0 = 0.f, a1 = 0.f, a2 = 0.f, a3 = 0.f;
#pragma unroll
        for (int g = 0; g < 4; ++g) {
            const float4 qv = qs4[g * 64 + lane];
            const float4 k0 = r0[g * 64 + lane];
            const float4 k1 = r1[g * 64 + lane];
            const float4 k2 = r2[g * 64 + lane];
            const float4 k3 = r3[g * 64 + lane];
            a0 += k0.x * qv.x + k0.y * qv.y + k0.z * qv.z + k0.w * qv.w;
            a1 += k1.x * qv.x + k1.y * qv.y + k1.z * qv.z + k1.w * qv.w;
            a2 += k2.x * qv.x + k2.y * qv.y + k2.z * qv.z + k2.w * qv.w;
            a3 += k3.x * qv.x + k3.y * qv.y + k3.z * qv.z + k3.w * qv.w;
        }
        a0 = wred(a0); a1 = wred(a1); a2 = wred(a2); a3 = wred(a3);
        if (lane == 0) {
            float* __restrict__ so = scores + (size_t)b * T + tb;
            so[0] = a0; so[1] = a1; so[2] = a2; so[3] = a3;
        }
    }
}

// ---------------------------------------------------------------------------
// Kernel 3: softmax over (T+1) scores per batch; appended score q.k inline.
// grid B, block 256.
__global__ __launch_bounds__(256) void softmax_kernel(const float* __restrict__ scores,
                                                      const float* __restrict__ qkv,
                                                      float* __restrict__ attn) {
    __shared__ float red[256];
    const int b = blockIdx.x, tid = threadIdx.x;
    const float* __restrict__ qp = qkv + 2 * (B * H) + (size_t)b * H;
    const float* __restrict__ kp = qkv + 1 * (B * H) + (size_t)b * H;

    const float4 qv = reinterpret_cast<const float4*>(qp)[tid];
    const float4 kv = reinterpret_cast<const float4*>(kp)[tid];
    red[tid] = qv.x * kv.x + qv.y * kv.y + qv.z * kv.z + qv.w * kv.w;
    __syncthreads();
    for (int s = 128; s; s >>= 1) {
        if (tid < s) red[tid] += red[tid + s];
        __syncthreads();
    }
    const float s_last = red[0];
    __syncthreads();

    float sc[16];
    const float* __restrict__ srow = scores + (size_t)b * T;
    float mx = s_last;
#pragma unroll
    for (int i = 0; i < 16; ++i) {
        sc[i] = srow[i * 256 + tid];
        mx = fmaxf(mx, sc[i]);
    }
    red[tid] = mx;
    __syncthreads();
    for (int s = 128; s; s >>= 1) {
        if (tid < s) red[tid] = fmaxf(red[tid], red[tid + s]);
        __syncthreads();
    }
    mx = red[0];
    __syncthreads();

    float sum = 0.f;
#pragma unroll
    for (int i = 0; i < 16; ++i) {
        sc[i] = expf(sc[i] - mx);
        sum += sc[i];
    }
    const float e_last = expf(s_last - mx);
    if (tid == 0) sum += e_last;
    red[tid] = sum;
    __syncthreads();
    for (int s = 128; s; s >>= 1) {
        if (tid < s) red[tid] += red[tid + s];
        __syncthreads();
    }
    const float inv = 1.f / red[0];

    float* __restrict__ arow = attn + (size_t)b * ATTN_STRIDE;
#pragma unroll
    for (int i = 0; i < 16; ++i) arow[i * 256 + tid] = sc[i] * inv;
    if (tid == 0) arow[T] = e_last * inv;
}

// ---------------------------------------------------------------------------
// Kernel 4: PV partials. grid (NTC, B), block 256; thread owns a float4 of h.
__global__ __launch_bounds__(256) void pv_partial(const float* __restrict__ vc,
                                                  const float* __restrict__ attn,
                                                  float* __restrict__ part2) {
    __shared__ float as[T / NTC];     // 64 attn weights
    const int tc = blockIdx.x, b = blockIdx.y, tid = threadIdx.x;
    const int t0 = tc * (T / NTC);
    if (tid < (T / NTC)) as[tid] = attn[(size_t)b * ATTN_STRIDE + t0 + tid];
    __syncthreads();

    const float4* __restrict__ vrow =
        reinterpret_cast<const float4*>(vc + ((size_t)b * T + t0) * H);
    float4 acc = {0.f, 0.f, 0.f, 0.f};
#pragma unroll 4
    for (int t = 0; t < (T / NTC); ++t) {
        const float a = as[t];
        const float4 vv = vrow[(size_t)t * 256 + tid];
        acc.x += a * vv.x; acc.y += a * vv.y;
        acc.z += a * vv.z; acc.w += a * vv.w;
    }
    reinterpret_cast<float4*>(part2 + ((size_t)b * NTC + tc) * H)[tid] = acc;
}

// ---------------------------------------------------------------------------
// Kernel 5: finalize. out = (sum_tc part2 + attn_last * v) / B + x.
// grid 128, block 256.
__global__ __launch_bounds__(256) void finalize_kernel(const float* __restrict__ part2,
                                                       const float* __restrict__ attn,
                                                       const float* __restrict__ qkv,
                                                       const float* __restrict__ x,
                                                       float* __restrict__ out) {
    const int idx = blockIdx.x * 256 + threadIdx.x;  // 0..32767
    const int b = idx >> 10;
    const int h = idx & 1023;
    float s = 0.f;
#pragma unroll
    for (int tc = 0; tc < NTC; ++tc)
        s += part2[((size_t)b * NTC + tc) * H + h];
    const float a_last = attn[(size_t)b * ATTN_STRIDE + T];
    const float v = qkv[(size_t)b * H + h];   // p=0 slot is value projection
    out[idx] = (s + a_last * v) * (1.f / 32.f) + x[idx];
}

// ---------------------------------------------------------------------------
extern "C" void kernel_launch(void* const* d_in, const int* in_sizes, int n_in,
                              void* d_out, int out_size, void* d_ws, size_t ws_size,
                              hipStream_t stream) {
    const float* x  = (const float*)d_in[0];
    const float* kc = (const float*)d_in[1];
    const float* vc = (const float*)d_in[2];
    const float* Wv = (const float*)d_in[3];
    const float* Wk = (const float*)d_in[4];
    const float* Wq = (const float*)d_in[5];
    float* out = (float*)d_out;
    float* ws  = (float*)d_ws;

    float* qkv    = ws + OFF_QKV;
    float* scores = ws + OFF_SCORES;
    float* attn   = ws + OFF_ATTN;
    float* part2  = ws + OFF_PART2;

    hipLaunchKernelGGL(proj_fused, dim3(16, 3, 2), dim3(256), 0, stream,
                       x, Wv, Wk, Wq, qkv);
    hipLaunchKernelGGL(scores_kernel, dim3(T / 64, B), dim3(256), 0, stream,
                       kc, qkv + 2 * (B * H), scores);
    hipLaunchKernelGGL(softmax_kernel, dim3(B), dim3(256), 0, stream,
                       scores, qkv, attn);
    hipLaunchKernelGGL(pv_partial, dim3(NTC, B), dim3(256), 0, stream,
                       vc, attn, part2);
    hipLaunchKernelGGL(finalize_kernel, dim3(128), dim3(256), 0, stream,
                       part2, attn, qkv, x, out);
}

// Round 3
// 220.789 us; speedup vs baseline: 1.3018x; 1.3018x over previous
//
#include <hip/hip_runtime.h>
#include <hip/hip_bf16.h>

// Problem constants
#define B 32
#define T 4096
#define E 1024
#define H 1024

// ws layout (in floats)
// qkv: p=0 -> v, p=1 -> k, p=2 -> q  (matches input order W_value, W_Key, W_Query)
#define OFF_QKV    0                       // 3 * 32 * 1024 = 98304
#define ECH        16
#define OFF_PART1  98304                   // 3 * ECH * 32 * 1024 = 1572864
#define OFF_SCORES (OFF_PART1 + 3*ECH*32*1024)   // 32 * 4096 = 131072
#define ATTN_STRIDE 4104
#define OFF_ATTN   (OFF_SCORES + 32*4096)  // 32 * 4104 = 131328
#define NTC        32                      // t-chunks for PV
#define OFF_PART2  (OFF_ATTN + 32*ATTN_STRIDE)   // 32 * NTC * 1024 = 1048576

// ---------------------------------------------------------------------------
// Kernel 1: projection partial sums.
// grid (ECH, 16, 3), block 256.  Each wave: 64 h-columns, 8 batches, 64 e's.
__global__ void proj_partial(const float* __restrict__ x,
                             const float* __restrict__ Wv,
                             const float* __restrict__ Wk,
                             const float* __restrict__ Wq,
                             float* __restrict__ part) {
    const int ec = blockIdx.x;       // e-chunk (64 e's)
    const int hc = blockIdx.y;       // h-chunk (64 h's)
    const int p  = blockIdx.z;       // which projection
    const float* __restrict__ W = (p == 0) ? Wv : ((p == 1) ? Wk : Wq);

    const int wave = threadIdx.x >> 6;
    const int lane = threadIdx.x & 63;
    const int h  = hc * 64 + lane;
    const int b0 = wave * 8;
    const int e0 = ec * 64;

    float acc[8] = {0.f, 0.f, 0.f, 0.f, 0.f, 0.f, 0.f, 0.f};

    for (int eg = 0; eg < 16; ++eg) {
        const int e = e0 + eg * 4;
        const float w0 = W[(size_t)(e + 0) * H + h];
        const float w1 = W[(size_t)(e + 1) * H + h];
        const float w2 = W[(size_t)(e + 2) * H + h];
        const float w3 = W[(size_t)(e + 3) * H + h];
#pragma unroll
        for (int j = 0; j < 8; ++j) {
            const float4 xv = *reinterpret_cast<const float4*>(&x[(b0 + j) * E + e]);
            acc[j] += xv.x * w0 + xv.y * w1 + xv.z * w2 + xv.w * w3;
        }
    }
#pragma unroll
    for (int j = 0; j < 8; ++j) {
        part[((size_t)(p * ECH + ec) * B + (b0 + j)) * H + h] = acc[j];
    }
}

// ---------------------------------------------------------------------------
// Kernel 2: reduce projection partials -> qkv.  grid 384, block 256.
__global__ void proj_reduce(const float* __restrict__ part,
                            float* __restrict__ qkv) {
    const int idx = blockIdx.x * 256 + threadIdx.x;   // 0 .. 3*32*1024-1
    const int p = idx >> 15;           // / 32768
    const int r = idx & 32767;         // b*1024 + h
    float s = 0.f;
#pragma unroll
    for (int ec = 0; ec < ECH; ++ec)
        s += part[(size_t)(p * ECH + ec) * (B * H) + r];
    qkv[(size_t)p * (B * H) + r] = s;
}

// ---------------------------------------------------------------------------
// Kernel 3: scores[b][t] = dot(key_cache[b][t][:], q[b][:]).
// grid (T/8, B), block 256 (4 waves); each wave handles 2 rows.
// q held in registers (4 float4/lane), no LDS, no syncthreads.
__global__ void scores_kernel(const float* __restrict__ kc,
                              const float* __restrict__ q,
                              float* __restrict__ scores) {
    const int b = blockIdx.y;
    const int wave = threadIdx.x >> 6;
    const int lane = threadIdx.x & 63;

    const float4* __restrict__ q4 = reinterpret_cast<const float4*>(q + (size_t)b * H);
    float4 qv[4];
#pragma unroll
    for (int g = 0; g < 4; ++g) qv[g] = q4[g * 64 + lane];

#pragma unroll
    for (int r = 0; r < 2; ++r) {
        const int t = blockIdx.x * 8 + wave * 2 + r;
        const float4* __restrict__ row =
            reinterpret_cast<const float4*>(kc + ((size_t)b * T + t) * H);
        float acc = 0.f;
#pragma unroll
        for (int g = 0; g < 4; ++g) {
            const float4 kv = row[g * 64 + lane];
            acc += kv.x * qv[g].x + kv.y * qv[g].y + kv.z * qv[g].z + kv.w * qv[g].w;
        }
#pragma unroll
        for (int m = 32; m; m >>= 1) acc += __shfl_xor(acc, m, 64);
        if (lane == 0) scores[(size_t)b * T + t] = acc;
    }
}

// ---------------------------------------------------------------------------
// Kernel 4: softmax over (T+1) scores per batch; computes appended score q.k.
// grid B, block 256.
__global__ void softmax_kernel(const float* __restrict__ scores,
                               const float* __restrict__ qkv,
                               float* __restrict__ attn) {
    __shared__ float red[256];
    const int b = blockIdx.x, tid = threadIdx.x;
    const float* __restrict__ qp = qkv + 2 * (B * H) + (size_t)b * H;
    const float* __restrict__ kp = qkv + 1 * (B * H) + (size_t)b * H;

    // appended-token score: dot(q, k)
    const float4 qv = reinterpret_cast<const float4*>(qp)[tid];
    const float4 kv = reinterpret_cast<const float4*>(kp)[tid];
    red[tid] = qv.x * kv.x + qv.y * kv.y + qv.z * kv.z + qv.w * kv.w;
    __syncthreads();
    for (int s = 128; s; s >>= 1) {
        if (tid < s) red[tid] += red[tid + s];
        __syncthreads();
    }
    const float s_last = red[0];
    __syncthreads();

    // local scores (strided, coalesced)
    float sc[16];
    const float* __restrict__ srow = scores + (size_t)b * T;
    float mx = s_last;
#pragma unroll
    for (int i = 0; i < 16; ++i) {
        sc[i] = srow[i * 256 + tid];
        mx = fmaxf(mx, sc[i]);
    }
    red[tid] = mx;
    __syncthreads();
    for (int s = 128; s; s >>= 1) {
        if (tid < s) red[tid] = fmaxf(red[tid], red[tid + s]);
        __syncthreads();
    }
    mx = red[0];
    __syncthreads();

    float sum = 0.f;
#pragma unroll
    for (int i = 0; i < 16; ++i) {
        sc[i] = expf(sc[i] - mx);
        sum += sc[i];
    }
    const float e_last = expf(s_last - mx);
    if (tid == 0) sum += e_last;
    red[tid] = sum;
    __syncthreads();
    for (int s = 128; s; s >>= 1) {
        if (tid < s) red[tid] += red[tid + s];
        __syncthreads();
    }
    const float inv = 1.f / red[0];

    float* __restrict__ arow = attn + (size_t)b * ATTN_STRIDE;
#pragma unroll
    for (int i = 0; i < 16; ++i) arow[i * 256 + tid] = sc[i] * inv;
    if (tid == 0) arow[T] = e_last * inv;
}

// ---------------------------------------------------------------------------
// Kernel 5: PV partials.  grid (NTC, B), block 256; thread owns a float4 of h.
__global__ void pv_partial(const float* __restrict__ vc,
                           const float* __restrict__ attn,
                           float* __restrict__ part2) {
    __shared__ float as[T / NTC];     // 128 attn weights
    const int tc = blockIdx.x, b = blockIdx.y, tid = threadIdx.x;
    const int t0 = tc * (T / NTC);
    if (tid < (T / NTC)) as[tid] = attn[(size_t)b * ATTN_STRIDE + t0 + tid];
    __syncthreads();

    const float4* __restrict__ vrow =
        reinterpret_cast<const float4*>(vc + ((size_t)b * T + t0) * H);
    float4 acc = {0.f, 0.f, 0.f, 0.f};
#pragma unroll 4
    for (int t = 0; t < (T / NTC); ++t) {
        const float a = as[t];
        const float4 vv = vrow[(size_t)t * 256 + tid];
        acc.x += a * vv.x; acc.y += a * vv.y;
        acc.z += a * vv.z; acc.w += a * vv.w;
    }
    reinterpret_cast<float4*>(part2 + ((size_t)b * NTC + tc) * H)[tid] = acc;
}

// ---------------------------------------------------------------------------
// Kernel 6: finalize.  out = (sum_tc part2 + attn_last * v) / B + x.
// grid 128, block 256.
__global__ void finalize_kernel(const float* __restrict__ part2,
                                const float* __restrict__ attn,
                                const float* __restrict__ qkv,
                                const float* __restrict__ x,
                                float* __restrict__ out) {
    const int idx = blockIdx.x * 256 + threadIdx.x;  // 0..32767
    const int b = idx >> 10;
    const int h = idx & 1023;
    float s = 0.f;
#pragma unroll
    for (int tc = 0; tc < NTC; ++tc)
        s += part2[((size_t)b * NTC + tc) * H + h];
    const float a_last = attn[(size_t)b * ATTN_STRIDE + T];
    const float v = qkv[(size_t)b * H + h];   // p=0 slot is value projection
    out[idx] = (s + a_last * v) * (1.f / 32.f) + x[idx];
}

// ---------------------------------------------------------------------------
extern "C" void kernel_launch(void* const* d_in, const int* in_sizes, int n_in,
                              void* d_out, int out_size, void* d_ws, size_t ws_size,
                              hipStream_t stream) {
    const float* x  = (const float*)d_in[0];
    const float* kc = (const float*)d_in[1];
    const float* vc = (const float*)d_in[2];
    const float* Wv = (const float*)d_in[3];
    const float* Wk = (const float*)d_in[4];
    const float* Wq = (const float*)d_in[5];
    float* out = (float*)d_out;
    float* ws  = (float*)d_ws;

    float* qkv    = ws + OFF_QKV;
    float* part1  = ws + OFF_PART1;
    float* scores = ws + OFF_SCORES;
    float* attn   = ws + OFF_ATTN;
    float* part2  = ws + OFF_PART2;

    hipLaunchKernelGGL(proj_partial, dim3(ECH, 16, 3), dim3(256), 0, stream,
                       x, Wv, Wk, Wq, part1);
    hipLaunchKernelGGL(proj_reduce, dim3(384), dim3(256), 0, stream,
                       part1, qkv);
    hipLaunchKernelGGL(scores_kernel, dim3(T / 8, B), dim3(256), 0, stream,
                       kc, qkv + 2 * (B * H), scores);
    hipLaunchKernelGGL(softmax_kernel, dim3(B), dim3(256), 0, stream,
                       scores, qkv, attn);
    hipLaunchKernelGGL(pv_partial, dim3(NTC, B), dim3(256), 0, stream,
                       vc, attn, part2);
    hipLaunchKernelGGL(finalize_kernel, dim3(128), dim3(256), 0, stream,
                       part2, attn, qkv, x, out);
}